// Round 10
// baseline (234.272 us; speedup 1.0000x reference)
//
#include <hip/hip_runtime.h>

// MSARowAttentionWithPairBias — round 16: split fused_pre + BW-aware reorder.
// r15 falsified register-starvation (compiler kept VGPR=32 under a 256 cap).
// fused_pre stuck at 47-50us across THREE internal rewrites -> cost is
// external: the harness's 256MiB fillBufferAligned (ws re-poison, 42us at
// 6.4TB/s, seen r12) overlaps our first in-stream kernel and starves it.
// 53MB of traffic measuring 47us =~ fill(42) + true work(~6). Fix+test:
// split into msa_wprep_k (feeds gemm0; absorbs fill window) and
// pair_bias_k (feeds attn only; runs in the clean window after gemm0).
// Order: msa_wprep -> gemm0 -> pair_bias -> attn -> gemm1 (deps respected;
// gvp aliases Am, dead after gemm0). Branch code verbatim from r15.
// Prediction: pair_bias 7-12us clean (theory A) vs ~40us (theory B) —
// either way next round has decisive per-kernel counters.

typedef _Float16 fp16;
typedef fp16 fp16x8 __attribute__((ext_vector_type(8)));
typedef fp16 fp16x4 __attribute__((ext_vector_type(4)));
typedef float floatx4 __attribute__((ext_vector_type(4)));

#define NM 8388608u            // 32768*256 elements

__device__ __forceinline__ void gld16(const fp16* g, fp16* l) {
  __builtin_amdgcn_global_load_lds(
      (const __attribute__((address_space(1))) unsigned int*)g,
      (__attribute__((address_space(3))) unsigned int*)l, 16, 0, 0);
}

// ---- msa-LN + weight prep (feeds gemm0) ------------------------------------
// blocks [0,2048): msa-LN, 16 rows/block (4 rows/wave)
// blocks [2048,2128): weight transpose via LDS tile (5 mats x 16 tiles)
__global__ __launch_bounds__(256) void msa_wprep_k(
    const float* __restrict__ msa, const float* __restrict__ ln_m_g,
    const float* __restrict__ ln_m_b, fp16* __restrict__ Am,
    const float* __restrict__ Wq, const float* __restrict__ Wk,
    const float* __restrict__ Wv, const float* __restrict__ Wg,
    const float* __restrict__ Wo, fp16* __restrict__ WT,
    fp16* __restrict__ WoT)
{
  __shared__ fp16 tileT[64][72];     // transpose branch only
  const int blk = blockIdx.x;
  const int t = threadIdx.x;

  if (blk < 2048) {
    // ------------- msa LayerNorm -> Am fp16, 4 rows/wave (ILP x4) ---------
    const int lane = t & 63;
    const int rbase = blk * 16 + (t >> 6) * 4;
    const float* xp = msa + (size_t)rbase * 256 + lane * 4;
    float4 v0 = *(const float4*)(xp);
    float4 v1 = *(const float4*)(xp + 256);
    float4 v2 = *(const float4*)(xp + 512);
    float4 v3 = *(const float4*)(xp + 768);

    float s0 = (v0.x+v0.y)+(v0.z+v0.w);
    float q0 = (v0.x*v0.x+v0.y*v0.y)+(v0.z*v0.z+v0.w*v0.w);
    float s1 = (v1.x+v1.y)+(v1.z+v1.w);
    float q1 = (v1.x*v1.x+v1.y*v1.y)+(v1.z*v1.z+v1.w*v1.w);
    float s2 = (v2.x+v2.y)+(v2.z+v2.w);
    float q2 = (v2.x*v2.x+v2.y*v2.y)+(v2.z*v2.z+v2.w*v2.w);
    float s3 = (v3.x+v3.y)+(v3.z+v3.w);
    float q3 = (v3.x*v3.x+v3.y*v3.y)+(v3.z*v3.z+v3.w*v3.w);
    #pragma unroll
    for (int mk = 32; mk >= 1; mk >>= 1) {   // 4 independent chains/level
      s0 += __shfl_xor(s0, mk); q0 += __shfl_xor(q0, mk);
      s1 += __shfl_xor(s1, mk); q1 += __shfl_xor(q1, mk);
      s2 += __shfl_xor(s2, mk); q2 += __shfl_xor(q2, mk);
      s3 += __shfl_xor(s3, mk); q3 += __shfl_xor(q3, mk);
    }
    float4 gg = *(const float4*)(ln_m_g + lane*4);
    float4 bb = *(const float4*)(ln_m_b + lane*4);
    fp16* op = Am + (size_t)rbase * 256 + lane * 4;

    #define LNSTORE(vv, sv, qv, ofs) do {                        \
      float mu = (sv) * (1.0f/256.0f);                           \
      float rs = rsqrtf((qv) * (1.0f/256.0f) - mu*mu + 1e-5f);   \
      fp16x4 o;                                                  \
      o[0] = (fp16)(((vv).x - mu) * rs * gg.x + bb.x);           \
      o[1] = (fp16)(((vv).y - mu) * rs * gg.y + bb.y);           \
      o[2] = (fp16)(((vv).z - mu) * rs * gg.z + bb.z);           \
      o[3] = (fp16)(((vv).w - mu) * rs * gg.w + bb.w);           \
      *(fp16x4*)(op + (ofs)) = o; } while (0)
    LNSTORE(v0, s0, q0, 0);
    LNSTORE(v1, s1, q1, 256);
    LNSTORE(v2, s2, q2, 512);
    LNSTORE(v3, s3, q3, 768);
    #undef LNSTORE

  } else {
    // ------- weight prep: 64x64 LDS tile transpose, fp32 -> fp16 ----------
    const int bid  = blk - 2048;         // 0..79
    const int mat  = bid >> 4;           // 0..4 (Wq,Wk,Wv,Wg,Wo)
    const int tile = bid & 15;
    const int tk = tile >> 2, tc = tile & 3;
    const float* W = (mat==0) ? Wq : (mat==1) ? Wk : (mat==2) ? Wv
                   : (mat==3) ? Wg : Wo;
    const int r  = t >> 2;               // 0..63 (source row)
    const int c4 = (t & 3) << 4;         // 0,16,32,48 (source col base)
    const float* src = W + (size_t)(tk*64 + r) * 256 + tc*64 + c4;
    #pragma unroll
    for (int e = 0; e < 4; ++e) {
      float4 vv = *(const float4*)(src + e*4);
      tileT[c4 + e*4 + 0][r] = (fp16)vv.x;
      tileT[c4 + e*4 + 1][r] = (fp16)vv.y;
      tileT[c4 + e*4 + 2][r] = (fp16)vv.z;
      tileT[c4 + e*4 + 3][r] = (fp16)vv.w;
    }
    __syncthreads();
    const int nl = t >> 2;               // 0..63 (output n within tile)
    const int k4 = (t & 3) << 4;         // output k base
    fp16* dst = (mat < 4)
        ? WT  + (size_t)(mat*256 + tc*64 + nl) * 256 + tk*64 + k4
        : WoT + (size_t)(tc*64 + nl) * 256 + tk*64 + k4;
    *(fp16x8*)(dst)     = *(const fp16x8*)&tileT[nl][k4];
    *(fp16x8*)(dst + 8) = *(const fp16x8*)&tileT[nl][k4 + 8];
  }
}

// ---- pair-LN + @Wp -> biasF (feeds attn only; runs in clean BW window) -----
__global__ __launch_bounds__(256) void pair_bias_k(
    const float* __restrict__ pair, const float* __restrict__ ln_p_g,
    const float* __restrict__ ln_p_b, const float* __restrict__ Wp,
    float* __restrict__ biasF)
{
  const int blk = blockIdx.x;
  const int t = threadIdx.x;
  const int w = t >> 6, lane = t & 63;
  const int grp = lane >> 3, sub = lane & 7;
  const int row = blk * 32 + w * 8 + grp;   // i*256 + j
  const int c0  = sub * 16;

  const float* pr = pair + (size_t)row * 128 + c0;
  float4 v[4];
  #pragma unroll
  for (int e = 0; e < 4; ++e) v[e] = *(const float4*)(pr + e*4);

  float s = 0.f, ss = 0.f;
  #pragma unroll
  for (int e = 0; e < 4; ++e) {
    s  += (v[e].x + v[e].y) + (v[e].z + v[e].w);
    ss += (v[e].x*v[e].x + v[e].y*v[e].y) + (v[e].z*v[e].z + v[e].w*v[e].w);
  }
  #pragma unroll
  for (int mk = 1; mk <= 4; mk <<= 1) {
    s  += __shfl_xor(s, mk);
    ss += __shfl_xor(ss, mk);
  }
  float mu  = s * (1.0f/128.0f);
  float var = ss * (1.0f/128.0f) - mu*mu;
  float rs  = rsqrtf(var + 1e-5f);

  float acc[8] = {0.f,0.f,0.f,0.f,0.f,0.f,0.f,0.f};
  #pragma unroll
  for (int e = 0; e < 4; ++e) {
    float4 gg = *(const float4*)(ln_p_g + c0 + e*4);
    float4 bb = *(const float4*)(ln_p_b + c0 + e*4);
    float p[4];
    p[0] = (v[e].x - mu) * rs * gg.x + bb.x;
    p[1] = (v[e].y - mu) * rs * gg.y + bb.y;
    p[2] = (v[e].z - mu) * rs * gg.z + bb.z;
    p[3] = (v[e].w - mu) * rs * gg.w + bb.w;
    #pragma unroll
    for (int u = 0; u < 4; ++u) {
      const float* wr = Wp + (c0 + e*4 + u) * 8;
      float4 w0 = *(const float4*)(wr);
      float4 w1 = *(const float4*)(wr + 4);
      acc[0] = fmaf(p[u], w0.x, acc[0]);
      acc[1] = fmaf(p[u], w0.y, acc[1]);
      acc[2] = fmaf(p[u], w0.z, acc[2]);
      acc[3] = fmaf(p[u], w0.w, acc[3]);
      acc[4] = fmaf(p[u], w1.x, acc[4]);
      acc[5] = fmaf(p[u], w1.y, acc[5]);
      acc[6] = fmaf(p[u], w1.z, acc[6]);
      acc[7] = fmaf(p[u], w1.w, acc[7]);
    }
  }
  #pragma unroll
  for (int mk = 1; mk <= 4; mk <<= 1)
    #pragma unroll
    for (int hh = 0; hh < 8; ++hh)
      acc[hh] += __shfl_xor(acc[hh], mk);

  int i = row >> 8, j = row & 255;
  biasF[sub * 65536 + (j >> 2) * 1024 + i * 4 + (j & 3)] = acc[sub];
}

// -------- MFMA GEMM (transposed product): C = A[Mx256] @ WT[Nx256]^T --------
// acc[ti][tj] = mfma(bf[tj], af[ti]) -> lane: m = ..+r16, n = ..+q*4+r.
// BK=64 as TWO 32-k halves, each in r8's verified 0-conflict layout:
// [rows][4 chunks of 16B], 64B row stride, chunk swizzle qs^((r>>1)&3) on
// the global source, read XOR q^((r16>>1)&3). 4 K-steps.
// launch_bounds(256,4): VGPR 64 + AGPR 64 = 128 == 512/4 cap -> 4 blocks/CU.
// TJ = tj tiles/wave: BN = 32*TJ. TJ=4 (mode 0) / TJ=2 (mode 1).
template<int TJ>
__global__ __launch_bounds__(256, 4) void mfma_gemm_k(
    const fp16* __restrict__ A, const fp16* __restrict__ BT,
    fp16* __restrict__ qkv, fp16* __restrict__ gG, float* __restrict__ outF,
    const float* __restrict__ bvec, int mode)
{
  __shared__ fp16 As[2][128 * 32];
  __shared__ fp16 Bs[2][TJ * 32 * 32];
  const int t  = threadIdx.x;
  const int bm = blockIdx.x * 128;
  const int bn = blockIdx.y * (32 * TJ);
  const int lane = t & 63;
  const int w  = t >> 6;
  const int wm = (w & 1) * 64, wn = (w >> 1) * (16 * TJ);
  const int r16 = lane & 15, q = lane >> 4;
  const int qa8 = (q ^ ((r16 >> 1) & 3)) * 8;   // swizzled read k-chunk

  // staging addresses (r8 pattern), hoisted out of the K-loop
  const int ca = t,        ra = ca >> 2;
  const int cb = 256 + t,  rb = cb >> 2;
  const int ka = ((ca & 3) ^ ((ra >> 1) & 3)) << 3;   // inverse-swizzled src
  const int kc = ((cb & 3) ^ ((rb >> 1) & 3)) << 3;
  const fp16* gA0 = A  + (size_t)(bm + ra) * 256 + ka;
  const fp16* gA1 = A  + (size_t)(bm + rb) * 256 + kc;
  const fp16* gB0 = BT + (size_t)(bn + ra) * 256 + ka;
  const fp16* gB1 = BT + (size_t)(bn + rb) * 256 + kc;   // TJ==4 only

  floatx4 acc[4][TJ];
  #pragma unroll
  for (int i = 0; i < 4; ++i)
    #pragma unroll
    for (int j = 0; j < TJ; ++j)
      acc[i][j] = (floatx4){0.f, 0.f, 0.f, 0.f};

  for (int kb = 0; kb < 256; kb += 64) {
    #pragma unroll
    for (int h = 0; h < 2; ++h) {
      gld16(gA0 + kb + h*32, &As[h][ca * 8]);
      gld16(gA1 + kb + h*32, &As[h][cb * 8]);
      gld16(gB0 + kb + h*32, &Bs[h][ca * 8]);
      if (TJ == 4) gld16(gB1 + kb + h*32, &Bs[h][cb * 8]);
    }
    __syncthreads();
    #pragma unroll
    for (int h = 0; h < 2; ++h) {
      fp16x8 af[4], bf[TJ];
      #pragma unroll
      for (int ti = 0; ti < 4; ++ti)
        af[ti] = *(const fp16x8*)&As[h][(wm + ti*16 + r16) * 32 + qa8];
      #pragma unroll
      for (int tj = 0; tj < TJ; ++tj)
        bf[tj] = *(const fp16x8*)&Bs[h][(wn + tj*16 + r16) * 32 + qa8];
      #pragma unroll
      for (int ti = 0; ti < 4; ++ti)
        #pragma unroll
        for (int tj = 0; tj < TJ; ++tj)
          acc[ti][tj] = __builtin_amdgcn_mfma_f32_16x16x32_f16(
              bf[tj], af[ti], acc[ti][tj], 0, 0, 0);   // transposed product
    }
    __syncthreads();
  }

  if (mode == 0) {
    #pragma unroll
    for (int ti = 0; ti < 4; ++ti) {
      int m = bm + wm + ti*16 + r16;
      #pragma unroll
      for (int tj = 0; tj < TJ; ++tj) {
        int n0 = bn + wn + tj*16 + q*4;
        int seg = n0 >> 8, c2 = n0 & 255;
        if (seg < 3) {
          fp16x4 pk;
          #pragma unroll
          for (int r = 0; r < 4; ++r) pk[r] = (fp16)acc[ti][tj][r];
          *(fp16x4*)(qkv + (size_t)seg * NM + (size_t)m * 256 + c2) = pk;
        } else {
          float4 bg4 = *(const float4*)(bvec + c2);
          fp16x4 o;
          o[0] = (fp16)(1.0f / (1.0f + __expf(-(acc[ti][tj][0] + bg4.x))));
          o[1] = (fp16)(1.0f / (1.0f + __expf(-(acc[ti][tj][1] + bg4.y))));
          o[2] = (fp16)(1.0f / (1.0f + __expf(-(acc[ti][tj][2] + bg4.z))));
          o[3] = (fp16)(1.0f / (1.0f + __expf(-(acc[ti][tj][3] + bg4.w))));
          // Gf fragment order: [d>>2][row][d&3], d = c2+r, row = m
          *(fp16x4*)(gG + (size_t)(c2 >> 2) * 131072 + (size_t)m * 4) = o;
        }
      }
    }
  } else {
    #pragma unroll
    for (int ti = 0; ti < 4; ++ti) {
      int m = bm + wm + ti*16 + r16;
      #pragma unroll
      for (int tj = 0; tj < TJ; ++tj) {
        int n0 = bn + wn + tj*16 + q*4;
        float4 bo4 = *(const float4*)(bvec + n0);
        float4 o;
        o.x = acc[ti][tj][0] + bo4.x;
        o.y = acc[ti][tj][1] + bo4.y;
        o.z = acc[ti][tj][2] + bo4.z;
        o.w = acc[ti][tj][3] + bo4.w;
        *(float4*)(outF + (size_t)m * 256 + n0) = o;
      }
    }
  }
}

// ---------------- MFMA flash attention: one block per (s,h) -----------------
// 4 waves x 64 i; 32-j chunks. S^T = K.Q^T; P -> per-wave LDS (bank-rotate
// swizzle); O^T = V^T.P^T. Bias float4 frag loads; G fp16x4 frag loads.
__global__ __launch_bounds__(256, 4) void attn_k(
    const fp16* __restrict__ Q, const fp16* __restrict__ K,
    const fp16* __restrict__ V, const fp16* __restrict__ Gf,
    const float* __restrict__ biasF, fp16* __restrict__ gv)
{
  __shared__ fp16 Vt[32 * 256];       // [d][j], col j ^ ((d&7)<<3)  (16 KB)
  __shared__ fp16 Pb[4][64 * 32];     // per-wave [il][jl], rotate swiz (16 KB)

  const int s = blockIdx.x, h = blockIdx.y;
  const int t = threadIdx.x;
  const int w = t >> 6, lane = t & 63;
  const int r16 = lane & 15, q = lane >> 4;
  const size_t base = ((size_t)s * 256) * 256 + h * 32;   // + row*256 + d

  // stage V -> Vt (transposed, swizzled)
  #pragma unroll
  for (int e = 0; e < 4; ++e) {
    int idx = e * 256 + t;
    int j = idx >> 2, d8 = (idx & 3) << 3;
    fp16x8 v = *(const fp16x8*)(V + base + (size_t)j * 256 + d8);
    #pragma unroll
    for (int u = 0; u < 8; ++u) {
      int d = d8 + u;
      Vt[d * 256 + (j ^ ((d & 7) << 3))] = v[u];
    }
  }
  __syncthreads();

  const int ibase = w * 64;
  fp16x8 qf[4];
  #pragma unroll
  for (int it = 0; it < 4; ++it)
    qf[it] = *(const fp16x8*)(Q + base + (size_t)(ibase + it*16 + r16) * 256 + q*8);

  floatx4 accO[2][4];                  // [dt][it], O^T tiles
  #pragma unroll
  for (int dt = 0; dt < 2; ++dt)
    #pragma unroll
    for (int it = 0; it < 4; ++it)
      accO[dt][it] = (floatx4){0.f, 0.f, 0.f, 0.f};
  float lp[4] = {0.f, 0.f, 0.f, 0.f};

  fp16* pb = &Pb[w][0];
  const float scale = 0.17677669529663687f;   // 1/sqrt(32)
  const float* bp = biasF + h * 65536;        // [j>>2][i][j&3]

  for (int jc = 0; jc < 8; ++jc) {
    const int j0 = jc * 32;
    fp16x8 kf[2];
    #pragma unroll
    for (int jt = 0; jt < 2; ++jt)
      kf[jt] = *(const fp16x8*)(K + base + (size_t)(j0 + jt*16 + r16) * 256 + q*8);

    floatx4 sc[2][4];                  // [jt][it]: row=j, col=i
    #pragma unroll
    for (int jt = 0; jt < 2; ++jt)
      #pragma unroll
      for (int it = 0; it < 4; ++it)
        sc[jt][it] = (floatx4){0.f, 0.f, 0.f, 0.f};
    #pragma unroll
    for (int jt = 0; jt < 2; ++jt)
      #pragma unroll
      for (int it = 0; it < 4; ++it)
        sc[jt][it] = __builtin_amdgcn_mfma_f32_16x16x32_f16(
            kf[jt], qf[it], sc[jt][it], 0, 0, 0);

    // bias (float4 frag load) + exp + row-sum partials + pack P to LDS
    #pragma unroll
    for (int jt = 0; jt < 2; ++jt) {
      #pragma unroll
      for (int it = 0; it < 4; ++it) {
        int i  = ibase + it*16 + r16;
        int jb = j0 + jt*16 + q*4;
        int il = it*16 + r16;
        float4 b4 = *(const float4*)(bp + (jb >> 2) * 1024 + i * 4);
        float x0 = __expf(fmaf(sc[jt][it][0], scale, b4.x));
        float x1 = __expf(fmaf(sc[jt][it][1], scale, b4.y));
        float x2 = __expf(fmaf(sc[jt][it][2], scale, b4.z));
        float x3 = __expf(fmaf(sc[jt][it][3], scale, b4.w));
        lp[it] += (x0 + x1) + (x2 + x3);
        fp16x4 p4;
        p4[0] = (fp16)x0; p4[1] = (fp16)x1; p4[2] = (fp16)x2; p4[3] = (fp16)x3;
        int colw = (jt*16 + q*4) ^ (((il >> 1) & 3) << 3);
        *(fp16x4*)&pb[il * 32 + colw] = p4;
      }
    }

    // O^T += V^T(chunk) . P^T(chunk), K=32 -> 1 k-step
    fp16x8 vf[2], pf[4];
    #pragma unroll
    for (int dt = 0; dt < 2; ++dt) {
      int d = dt*16 + r16;
      vf[dt] = *(const fp16x8*)&Vt[d * 256 + ((j0 + q*8) ^ ((d & 7) << 3))];
    }
    #pragma unroll
    for (int it = 0; it < 4; ++it) {
      int il = it*16 + r16;
      pf[it] = *(const fp16x8*)&pb[il * 32 + ((q*8) ^ (((il >> 1) & 3) << 3))];
    }
    #pragma unroll
    for (int dt = 0; dt < 2; ++dt)
      #pragma unroll
      for (int it = 0; it < 4; ++it)
        accO[dt][it] = __builtin_amdgcn_mfma_f32_16x16x32_f16(
            vf[dt], pf[it], accO[dt][it], 0, 0, 0);
  }

  // full row sums: reduce across q-groups
  #pragma unroll
  for (int mk = 16; mk <= 32; mk <<= 1)
    #pragma unroll
    for (int it = 0; it < 4; ++it)
      lp[it] += __shfl_xor(lp[it], mk);

  // epilogue: lane col i = r16, rows d = dt*16 + q*4 + r
  #pragma unroll
  for (int it = 0; it < 4; ++it) {
    float invl = 1.0f / lp[it];
    int i = ibase + it*16 + r16;
    size_t row = (size_t)s * 256 + i;
    #pragma unroll
    for (int dt = 0; dt < 2; ++dt) {
      int d0 = h*32 + dt*16 + q*4;
      fp16x4 g4 = *(const fp16x4*)(Gf + (size_t)(d0 >> 2) * 131072 + row * 4);
      fp16x4 o4;
      #pragma unroll
      for (int r = 0; r < 4; ++r)
        o4[r] = (fp16)((float)g4[r] * accO[dt][it][r] * invl);
      *(fp16x4*)(gv + row * 256 + d0) = o4;
    }
  }
}

extern "C" void kernel_launch(void* const* d_in, const int* in_sizes, int n_in,
                              void* d_out, int out_size, void* d_ws, size_t ws_size,
                              hipStream_t stream) {
  const float* msa    = (const float*)d_in[0];
  const float* pair   = (const float*)d_in[1];
  const float* ln_m_g = (const float*)d_in[2];
  const float* ln_m_b = (const float*)d_in[3];
  const float* ln_p_g = (const float*)d_in[4];
  const float* ln_p_b = (const float*)d_in[5];
  const float* Wq     = (const float*)d_in[6];
  const float* Wk     = (const float*)d_in[7];
  const float* Wv     = (const float*)d_in[8];
  const float* Wp     = (const float*)d_in[9];
  const float* Wg     = (const float*)d_in[10];
  const float* bg     = (const float*)d_in[11];
  const float* Wo     = (const float*)d_in[12];
  const float* bo     = (const float*)d_in[13];
  float* out = (float*)d_out;

  char* wsb = (char*)d_ws;
  fp16*  Am      = (fp16*)(wsb);                     // 16 MB [32768][256]
  fp16*  QKV16   = (fp16*)(wsb + 16777216);          // 48 MB 3 x [32768][256]
  fp16*  Gfb     = (fp16*)(wsb + 67108864);          // 16 MB [64][32768][4]
  float* biasF   = (float*)(wsb + 83886080);         //  2 MB [8][64][256][4]
  fp16*  WqkvgT  = (fp16*)(wsb + 85983232);          // .5 MB [1024][256]
  fp16*  WoT     = (fp16*)(wsb + 86507520);          // .13MB [256][256]
  fp16*  gvp     = Am;                               // alias: Am dead after QKVG

  // Order: msa_wprep (absorbs ws-poison fill overlap) -> gemm0 (compute-
  // bound, overlaps fill tail) -> pair_bias (clean BW window) -> attn -> gemm1
  msa_wprep_k<<<2128, 256, 0, stream>>>(msa, ln_m_g, ln_m_b, Am,
                                        Wq, Wk, Wv, Wg, Wo, WqkvgT, WoT);

  mfma_gemm_k<4><<<dim3(256, 8), 256, 0, stream>>>(Am, WqkvgT, QKV16, Gfb,
                                                   nullptr, bg, 0);

  pair_bias_k<<<2048, 256, 0, stream>>>(pair, ln_p_g, ln_p_b, Wp, biasF);

  attn_k<<<dim3(128, 8), 256, 0, stream>>>(QKV16, QKV16 + NM, QKV16 + 2*NM,
                                           Gfb, biasF, gvp);

  mfma_gemm_k<2><<<dim3(256, 4), 256, 0, stream>>>(gvp, WoT, nullptr, nullptr,
                                                   out, bo, 1);
}

// Round 11
// 208.419 us; speedup vs baseline: 1.1240x; 1.1240x over previous
//
#include <hip/hip_runtime.h>

// MSARowAttentionWithPairBias — round 17: pair_bias's 40-load chain -> LDS.
// r16 falsified fill-overlap: pair_bias standalone = 40us at 6% BW / 6.5%
// VALU / 0 conflicts. Common factor across ALL four 40-50us variants: ~40
// small global loads/wave (32x Wp-16B + 8x g/b) serialized at L2 latency
// (VGPR=32 load->consume chains; Wp/g/b thrashed out of L1 by the pair
// stream). Fix: stage Wp (4KB, XOR-swizzled: slot = s ^ ((s>>5)&7), read
// key (2R+h)^sub matches since R>>4==sub -> 8 distinct bank-quads across
// sub, broadcast across grp) + g/b (1KB) into LDS once per block; inner
// loop reads LDS (~5-12cy, broadcast) instead of global. VMEM/wave 45->~7.
// Everything else verbatim from r16.

typedef _Float16 fp16;
typedef fp16 fp16x8 __attribute__((ext_vector_type(8)));
typedef fp16 fp16x4 __attribute__((ext_vector_type(4)));
typedef float floatx4 __attribute__((ext_vector_type(4)));

#define NM 8388608u            // 32768*256 elements

__device__ __forceinline__ void gld16(const fp16* g, fp16* l) {
  __builtin_amdgcn_global_load_lds(
      (const __attribute__((address_space(1))) unsigned int*)g,
      (__attribute__((address_space(3))) unsigned int*)l, 16, 0, 0);
}

// ---- msa-LN + weight prep (feeds gemm0) ------------------------------------
// blocks [0,2048): msa-LN, 16 rows/block (4 rows/wave)
// blocks [2048,2128): weight transpose via LDS tile (5 mats x 16 tiles)
__global__ __launch_bounds__(256) void msa_wprep_k(
    const float* __restrict__ msa, const float* __restrict__ ln_m_g,
    const float* __restrict__ ln_m_b, fp16* __restrict__ Am,
    const float* __restrict__ Wq, const float* __restrict__ Wk,
    const float* __restrict__ Wv, const float* __restrict__ Wg,
    const float* __restrict__ Wo, fp16* __restrict__ WT,
    fp16* __restrict__ WoT)
{
  __shared__ fp16 tileT[64][72];     // transpose branch only
  const int blk = blockIdx.x;
  const int t = threadIdx.x;

  if (blk < 2048) {
    // ------------- msa LayerNorm -> Am fp16, 4 rows/wave (ILP x4) ---------
    const int lane = t & 63;
    const int rbase = blk * 16 + (t >> 6) * 4;
    const float* xp = msa + (size_t)rbase * 256 + lane * 4;
    float4 v0 = *(const float4*)(xp);
    float4 v1 = *(const float4*)(xp + 256);
    float4 v2 = *(const float4*)(xp + 512);
    float4 v3 = *(const float4*)(xp + 768);

    float s0 = (v0.x+v0.y)+(v0.z+v0.w);
    float q0 = (v0.x*v0.x+v0.y*v0.y)+(v0.z*v0.z+v0.w*v0.w);
    float s1 = (v1.x+v1.y)+(v1.z+v1.w);
    float q1 = (v1.x*v1.x+v1.y*v1.y)+(v1.z*v1.z+v1.w*v1.w);
    float s2 = (v2.x+v2.y)+(v2.z+v2.w);
    float q2 = (v2.x*v2.x+v2.y*v2.y)+(v2.z*v2.z+v2.w*v2.w);
    float s3 = (v3.x+v3.y)+(v3.z+v3.w);
    float q3 = (v3.x*v3.x+v3.y*v3.y)+(v3.z*v3.z+v3.w*v3.w);
    #pragma unroll
    for (int mk = 32; mk >= 1; mk >>= 1) {   // 4 independent chains/level
      s0 += __shfl_xor(s0, mk); q0 += __shfl_xor(q0, mk);
      s1 += __shfl_xor(s1, mk); q1 += __shfl_xor(q1, mk);
      s2 += __shfl_xor(s2, mk); q2 += __shfl_xor(q2, mk);
      s3 += __shfl_xor(s3, mk); q3 += __shfl_xor(q3, mk);
    }
    float4 gg = *(const float4*)(ln_m_g + lane*4);
    float4 bb = *(const float4*)(ln_m_b + lane*4);
    fp16* op = Am + (size_t)rbase * 256 + lane * 4;

    #define LNSTORE(vv, sv, qv, ofs) do {                        \
      float mu = (sv) * (1.0f/256.0f);                           \
      float rs = rsqrtf((qv) * (1.0f/256.0f) - mu*mu + 1e-5f);   \
      fp16x4 o;                                                  \
      o[0] = (fp16)(((vv).x - mu) * rs * gg.x + bb.x);           \
      o[1] = (fp16)(((vv).y - mu) * rs * gg.y + bb.y);           \
      o[2] = (fp16)(((vv).z - mu) * rs * gg.z + bb.z);           \
      o[3] = (fp16)(((vv).w - mu) * rs * gg.w + bb.w);           \
      *(fp16x4*)(op + (ofs)) = o; } while (0)
    LNSTORE(v0, s0, q0, 0);
    LNSTORE(v1, s1, q1, 256);
    LNSTORE(v2, s2, q2, 512);
    LNSTORE(v3, s3, q3, 768);
    #undef LNSTORE

  } else {
    // ------- weight prep: 64x64 LDS tile transpose, fp32 -> fp16 ----------
    const int bid  = blk - 2048;         // 0..79
    const int mat  = bid >> 4;           // 0..4 (Wq,Wk,Wv,Wg,Wo)
    const int tile = bid & 15;
    const int tk = tile >> 2, tc = tile & 3;
    const float* W = (mat==0) ? Wq : (mat==1) ? Wk : (mat==2) ? Wv
                   : (mat==3) ? Wg : Wo;
    const int r  = t >> 2;               // 0..63 (source row)
    const int c4 = (t & 3) << 4;         // 0,16,32,48 (source col base)
    const float* src = W + (size_t)(tk*64 + r) * 256 + tc*64 + c4;
    #pragma unroll
    for (int e = 0; e < 4; ++e) {
      float4 vv = *(const float4*)(src + e*4);
      tileT[c4 + e*4 + 0][r] = (fp16)vv.x;
      tileT[c4 + e*4 + 1][r] = (fp16)vv.y;
      tileT[c4 + e*4 + 2][r] = (fp16)vv.z;
      tileT[c4 + e*4 + 3][r] = (fp16)vv.w;
    }
    __syncthreads();
    const int nl = t >> 2;               // 0..63 (output n within tile)
    const int k4 = (t & 3) << 4;         // output k base
    fp16* dst = (mat < 4)
        ? WT  + (size_t)(mat*256 + tc*64 + nl) * 256 + tk*64 + k4
        : WoT + (size_t)(tc*64 + nl) * 256 + tk*64 + k4;
    *(fp16x8*)(dst)     = *(const fp16x8*)&tileT[nl][k4];
    *(fp16x8*)(dst + 8) = *(const fp16x8*)&tileT[nl][k4 + 8];
  }
}

// ---- pair-LN + @Wp -> biasF (frag order) -----------------------------------
// Wp/g/b staged in LDS once per block; inner loop is pure LDS + VALU.
// Wp swizzle: global 16B-chunk s lives at LDS slot s ^ ((s>>5)&7). Read of
// row R (=c0+e*4+u) chunk h: slot (2R+h) ^ sub (valid: (2R+h)>>5 == R>>4
// == sub) -> bank quad ((2u+h)^sub)&7 distinct across sub; same-sub lanes
// (different grp) broadcast.
__global__ __launch_bounds__(256) void pair_bias_k(
    const float* __restrict__ pair, const float* __restrict__ ln_p_g,
    const float* __restrict__ ln_p_b, const float* __restrict__ Wp,
    float* __restrict__ biasF)
{
  __shared__ __align__(16) float sW[1280];   // [0,1024): Wp swz; [1024,1152): g; [1152,1280): b
  const int blk = blockIdx.x;
  const int t = threadIdx.x;
  const int w = t >> 6, lane = t & 63;
  const int grp = lane >> 3, sub = lane & 7;
  const int row = blk * 32 + w * 8 + grp;   // i*256 + j
  const int c0  = sub * 16;

  // stage Wp (swizzled) + g + b
  {
    float4 wv = *(const float4*)(Wp + t * 4);          // 4KB, coalesced
    *(float4*)&sW[(t ^ ((t >> 5) & 7)) * 4] = wv;
    if (t < 32) {
      *(float4*)&sW[1024 + t*4] = *(const float4*)(ln_p_g + t*4);
      *(float4*)&sW[1152 + t*4] = *(const float4*)(ln_p_b + t*4);
    }
  }

  const float* pr = pair + (size_t)row * 128 + c0;
  float4 v[4];
  #pragma unroll
  for (int e = 0; e < 4; ++e) v[e] = *(const float4*)(pr + e*4);

  __syncthreads();

  float s = 0.f, ss = 0.f;
  #pragma unroll
  for (int e = 0; e < 4; ++e) {
    s  += (v[e].x + v[e].y) + (v[e].z + v[e].w);
    ss += (v[e].x*v[e].x + v[e].y*v[e].y) + (v[e].z*v[e].z + v[e].w*v[e].w);
  }
  #pragma unroll
  for (int mk = 1; mk <= 4; mk <<= 1) {
    s  += __shfl_xor(s, mk);
    ss += __shfl_xor(ss, mk);
  }
  float mu  = s * (1.0f/128.0f);
  float var = ss * (1.0f/128.0f) - mu*mu;
  float rs  = rsqrtf(var + 1e-5f);

  float acc[8] = {0.f,0.f,0.f,0.f,0.f,0.f,0.f,0.f};
  #pragma unroll
  for (int e = 0; e < 4; ++e) {
    float4 gg = *(const float4*)&sW[1024 + c0 + e*4];
    float4 bb = *(const float4*)&sW[1152 + c0 + e*4];
    float p[4];
    p[0] = (v[e].x - mu) * rs * gg.x + bb.x;
    p[1] = (v[e].y - mu) * rs * gg.y + bb.y;
    p[2] = (v[e].z - mu) * rs * gg.z + bb.z;
    p[3] = (v[e].w - mu) * rs * gg.w + bb.w;
    #pragma unroll
    for (int u = 0; u < 4; ++u) {
      int R = c0 + e*4 + u;
      float4 w0 = *(const float4*)&sW[((2*R)     ^ sub) * 4];
      float4 w1 = *(const float4*)&sW[((2*R + 1) ^ sub) * 4];
      acc[0] = fmaf(p[u], w0.x, acc[0]);
      acc[1] = fmaf(p[u], w0.y, acc[1]);
      acc[2] = fmaf(p[u], w0.z, acc[2]);
      acc[3] = fmaf(p[u], w0.w, acc[3]);
      acc[4] = fmaf(p[u], w1.x, acc[4]);
      acc[5] = fmaf(p[u], w1.y, acc[5]);
      acc[6] = fmaf(p[u], w1.z, acc[6]);
      acc[7] = fmaf(p[u], w1.w, acc[7]);
    }
  }
  #pragma unroll
  for (int mk = 1; mk <= 4; mk <<= 1)
    #pragma unroll
    for (int hh = 0; hh < 8; ++hh)
      acc[hh] += __shfl_xor(acc[hh], mk);

  int i = row >> 8, j = row & 255;
  biasF[sub * 65536 + (j >> 2) * 1024 + i * 4 + (j & 3)] = acc[sub];
}

// -------- MFMA GEMM (transposed product): C = A[Mx256] @ WT[Nx256]^T --------
// acc[ti][tj] = mfma(bf[tj], af[ti]) -> lane: m = ..+r16, n = ..+q*4+r.
// BK=64 as TWO 32-k halves, each in r8's verified 0-conflict layout:
// [rows][4 chunks of 16B], 64B row stride, chunk swizzle qs^((r>>1)&3) on
// the global source, read XOR q^((r16>>1)&3). 4 K-steps.
// launch_bounds(256,4): VGPR 64 + AGPR 64 = 128 == 512/4 cap -> 4 blocks/CU.
// TJ = tj tiles/wave: BN = 32*TJ. TJ=4 (mode 0) / TJ=2 (mode 1).
template<int TJ>
__global__ __launch_bounds__(256, 4) void mfma_gemm_k(
    const fp16* __restrict__ A, const fp16* __restrict__ BT,
    fp16* __restrict__ qkv, fp16* __restrict__ gG, float* __restrict__ outF,
    const float* __restrict__ bvec, int mode)
{
  __shared__ fp16 As[2][128 * 32];
  __shared__ fp16 Bs[2][TJ * 32 * 32];
  const int t  = threadIdx.x;
  const int bm = blockIdx.x * 128;
  const int bn = blockIdx.y * (32 * TJ);
  const int lane = t & 63;
  const int w  = t >> 6;
  const int wm = (w & 1) * 64, wn = (w >> 1) * (16 * TJ);
  const int r16 = lane & 15, q = lane >> 4;
  const int qa8 = (q ^ ((r16 >> 1) & 3)) * 8;   // swizzled read k-chunk

  // staging addresses (r8 pattern), hoisted out of the K-loop
  const int ca = t,        ra = ca >> 2;
  const int cb = 256 + t,  rb = cb >> 2;
  const int ka = ((ca & 3) ^ ((ra >> 1) & 3)) << 3;   // inverse-swizzled src
  const int kc = ((cb & 3) ^ ((rb >> 1) & 3)) << 3;
  const fp16* gA0 = A  + (size_t)(bm + ra) * 256 + ka;
  const fp16* gA1 = A  + (size_t)(bm + rb) * 256 + kc;
  const fp16* gB0 = BT + (size_t)(bn + ra) * 256 + ka;
  const fp16* gB1 = BT + (size_t)(bn + rb) * 256 + kc;   // TJ==4 only

  floatx4 acc[4][TJ];
  #pragma unroll
  for (int i = 0; i < 4; ++i)
    #pragma unroll
    for (int j = 0; j < TJ; ++j)
      acc[i][j] = (floatx4){0.f, 0.f, 0.f, 0.f};

  for (int kb = 0; kb < 256; kb += 64) {
    #pragma unroll
    for (int h = 0; h < 2; ++h) {
      gld16(gA0 + kb + h*32, &As[h][ca * 8]);
      gld16(gA1 + kb + h*32, &As[h][cb * 8]);
      gld16(gB0 + kb + h*32, &Bs[h][ca * 8]);
      if (TJ == 4) gld16(gB1 + kb + h*32, &Bs[h][cb * 8]);
    }
    __syncthreads();
    #pragma unroll
    for (int h = 0; h < 2; ++h) {
      fp16x8 af[4], bf[TJ];
      #pragma unroll
      for (int ti = 0; ti < 4; ++ti)
        af[ti] = *(const fp16x8*)&As[h][(wm + ti*16 + r16) * 32 + qa8];
      #pragma unroll
      for (int tj = 0; tj < TJ; ++tj)
        bf[tj] = *(const fp16x8*)&Bs[h][(wn + tj*16 + r16) * 32 + qa8];
      #pragma unroll
      for (int ti = 0; ti < 4; ++ti)
        #pragma unroll
        for (int tj = 0; tj < TJ; ++tj)
          acc[ti][tj] = __builtin_amdgcn_mfma_f32_16x16x32_f16(
              bf[tj], af[ti], acc[ti][tj], 0, 0, 0);   // transposed product
    }
    __syncthreads();
  }

  if (mode == 0) {
    #pragma unroll
    for (int ti = 0; ti < 4; ++ti) {
      int m = bm + wm + ti*16 + r16;
      #pragma unroll
      for (int tj = 0; tj < TJ; ++tj) {
        int n0 = bn + wn + tj*16 + q*4;
        int seg = n0 >> 8, c2 = n0 & 255;
        if (seg < 3) {
          fp16x4 pk;
          #pragma unroll
          for (int r = 0; r < 4; ++r) pk[r] = (fp16)acc[ti][tj][r];
          *(fp16x4*)(qkv + (size_t)seg * NM + (size_t)m * 256 + c2) = pk;
        } else {
          float4 bg4 = *(const float4*)(bvec + c2);
          fp16x4 o;
          o[0] = (fp16)(1.0f / (1.0f + __expf(-(acc[ti][tj][0] + bg4.x))));
          o[1] = (fp16)(1.0f / (1.0f + __expf(-(acc[ti][tj][1] + bg4.y))));
          o[2] = (fp16)(1.0f / (1.0f + __expf(-(acc[ti][tj][2] + bg4.z))));
          o[3] = (fp16)(1.0f / (1.0f + __expf(-(acc[ti][tj][3] + bg4.w))));
          // Gf fragment order: [d>>2][row][d&3], d = c2+r, row = m
          *(fp16x4*)(gG + (size_t)(c2 >> 2) * 131072 + (size_t)m * 4) = o;
        }
      }
    }
  } else {
    #pragma unroll
    for (int ti = 0; ti < 4; ++ti) {
      int m = bm + wm + ti*16 + r16;
      #pragma unroll
      for (int tj = 0; tj < TJ; ++tj) {
        int n0 = bn + wn + tj*16 + q*4;
        float4 bo4 = *(const float4*)(bvec + n0);
        float4 o;
        o.x = acc[ti][tj][0] + bo4.x;
        o.y = acc[ti][tj][1] + bo4.y;
        o.z = acc[ti][tj][2] + bo4.z;
        o.w = acc[ti][tj][3] + bo4.w;
        *(float4*)(outF + (size_t)m * 256 + n0) = o;
      }
    }
  }
}

// ---------------- MFMA flash attention: one block per (s,h) -----------------
// 4 waves x 64 i; 32-j chunks. S^T = K.Q^T; P -> per-wave LDS (bank-rotate
// swizzle); O^T = V^T.P^T. Bias float4 frag loads; G fp16x4 frag loads.
__global__ __launch_bounds__(256, 4) void attn_k(
    const fp16* __restrict__ Q, const fp16* __restrict__ K,
    const fp16* __restrict__ V, const fp16* __restrict__ Gf,
    const float* __restrict__ biasF, fp16* __restrict__ gv)
{
  __shared__ fp16 Vt[32 * 256];       // [d][j], col j ^ ((d&7)<<3)  (16 KB)
  __shared__ fp16 Pb[4][64 * 32];     // per-wave [il][jl], rotate swiz (16 KB)

  const int s = blockIdx.x, h = blockIdx.y;
  const int t = threadIdx.x;
  const int w = t >> 6, lane = t & 63;
  const int r16 = lane & 15, q = lane >> 4;
  const size_t base = ((size_t)s * 256) * 256 + h * 32;   // + row*256 + d

  // stage V -> Vt (transposed, swizzled)
  #pragma unroll
  for (int e = 0; e < 4; ++e) {
    int idx = e * 256 + t;
    int j = idx >> 2, d8 = (idx & 3) << 3;
    fp16x8 v = *(const fp16x8*)(V + base + (size_t)j * 256 + d8);
    #pragma unroll
    for (int u = 0; u < 8; ++u) {
      int d = d8 + u;
      Vt[d * 256 + (j ^ ((d & 7) << 3))] = v[u];
    }
  }
  __syncthreads();

  const int ibase = w * 64;
  fp16x8 qf[4];
  #pragma unroll
  for (int it = 0; it < 4; ++it)
    qf[it] = *(const fp16x8*)(Q + base + (size_t)(ibase + it*16 + r16) * 256 + q*8);

  floatx4 accO[2][4];                  // [dt][it], O^T tiles
  #pragma unroll
  for (int dt = 0; dt < 2; ++dt)
    #pragma unroll
    for (int it = 0; it < 4; ++it)
      accO[dt][it] = (floatx4){0.f, 0.f, 0.f, 0.f};
  float lp[4] = {0.f, 0.f, 0.f, 0.f};

  fp16* pb = &Pb[w][0];
  const float scale = 0.17677669529663687f;   // 1/sqrt(32)
  const float* bp = biasF + h * 65536;        // [j>>2][i][j&3]

  for (int jc = 0; jc < 8; ++jc) {
    const int j0 = jc * 32;
    fp16x8 kf[2];
    #pragma unroll
    for (int jt = 0; jt < 2; ++jt)
      kf[jt] = *(const fp16x8*)(K + base + (size_t)(j0 + jt*16 + r16) * 256 + q*8);

    floatx4 sc[2][4];                  // [jt][it]: row=j, col=i
    #pragma unroll
    for (int jt = 0; jt < 2; ++jt)
      #pragma unroll
      for (int it = 0; it < 4; ++it)
        sc[jt][it] = (floatx4){0.f, 0.f, 0.f, 0.f};
    #pragma unroll
    for (int jt = 0; jt < 2; ++jt)
      #pragma unroll
      for (int it = 0; it < 4; ++it)
        sc[jt][it] = __builtin_amdgcn_mfma_f32_16x16x32_f16(
            kf[jt], qf[it], sc[jt][it], 0, 0, 0);

    // bias (float4 frag load) + exp + row-sum partials + pack P to LDS
    #pragma unroll
    for (int jt = 0; jt < 2; ++jt) {
      #pragma unroll
      for (int it = 0; it < 4; ++it) {
        int i  = ibase + it*16 + r16;
        int jb = j0 + jt*16 + q*4;
        int il = it*16 + r16;
        float4 b4 = *(const float4*)(bp + (jb >> 2) * 1024 + i * 4);
        float x0 = __expf(fmaf(sc[jt][it][0], scale, b4.x));
        float x1 = __expf(fmaf(sc[jt][it][1], scale, b4.y));
        float x2 = __expf(fmaf(sc[jt][it][2], scale, b4.z));
        float x3 = __expf(fmaf(sc[jt][it][3], scale, b4.w));
        lp[it] += (x0 + x1) + (x2 + x3);
        fp16x4 p4;
        p4[0] = (fp16)x0; p4[1] = (fp16)x1; p4[2] = (fp16)x2; p4[3] = (fp16)x3;
        int colw = (jt*16 + q*4) ^ (((il >> 1) & 3) << 3);
        *(fp16x4*)&pb[il * 32 + colw] = p4;
      }
    }

    // O^T += V^T(chunk) . P^T(chunk), K=32 -> 1 k-step
    fp16x8 vf[2], pf[4];
    #pragma unroll
    for (int dt = 0; dt < 2; ++dt) {
      int d = dt*16 + r16;
      vf[dt] = *(const fp16x8*)&Vt[d * 256 + ((j0 + q*8) ^ ((d & 7) << 3))];
    }
    #pragma unroll
    for (int it = 0; it < 4; ++it) {
      int il = it*16 + r16;
      pf[it] = *(const fp16x8*)&pb[il * 32 + ((q*8) ^ (((il >> 1) & 3) << 3))];
    }
    #pragma unroll
    for (int dt = 0; dt < 2; ++dt)
      #pragma unroll
      for (int it = 0; it < 4; ++it)
        accO[dt][it] = __builtin_amdgcn_mfma_f32_16x16x32_f16(
            vf[dt], pf[it], accO[dt][it], 0, 0, 0);
  }

  // full row sums: reduce across q-groups
  #pragma unroll
  for (int mk = 16; mk <= 32; mk <<= 1)
    #pragma unroll
    for (int it = 0; it < 4; ++it)
      lp[it] += __shfl_xor(lp[it], mk);

  // epilogue: lane col i = r16, rows d = dt*16 + q*4 + r
  #pragma unroll
  for (int it = 0; it < 4; ++it) {
    float invl = 1.0f / lp[it];
    int i = ibase + it*16 + r16;
    size_t row = (size_t)s * 256 + i;
    #pragma unroll
    for (int dt = 0; dt < 2; ++dt) {
      int d0 = h*32 + dt*16 + q*4;
      fp16x4 g4 = *(const fp16x4*)(Gf + (size_t)(d0 >> 2) * 131072 + row * 4);
      fp16x4 o4;
      #pragma unroll
      for (int r = 0; r < 4; ++r)
        o4[r] = (fp16)((float)g4[r] * accO[dt][it][r] * invl);
      *(fp16x4*)(gv + row * 256 + d0) = o4;
    }
  }
}

extern "C" void kernel_launch(void* const* d_in, const int* in_sizes, int n_in,
                              void* d_out, int out_size, void* d_ws, size_t ws_size,
                              hipStream_t stream) {
  const float* msa    = (const float*)d_in[0];
  const float* pair   = (const float*)d_in[1];
  const float* ln_m_g = (const float*)d_in[2];
  const float* ln_m_b = (const float*)d_in[3];
  const float* ln_p_g = (const float*)d_in[4];
  const float* ln_p_b = (const float*)d_in[5];
  const float* Wq     = (const float*)d_in[6];
  const float* Wk     = (const float*)d_in[7];
  const float* Wv     = (const float*)d_in[8];
  const float* Wp     = (const float*)d_in[9];
  const float* Wg     = (const float*)d_in[10];
  const float* bg     = (const float*)d_in[11];
  const float* Wo     = (const float*)d_in[12];
  const float* bo     = (const float*)d_in[13];
  float* out = (float*)d_out;

  char* wsb = (char*)d_ws;
  fp16*  Am      = (fp16*)(wsb);                     // 16 MB [32768][256]
  fp16*  QKV16   = (fp16*)(wsb + 16777216);          // 48 MB 3 x [32768][256]
  fp16*  Gfb     = (fp16*)(wsb + 67108864);          // 16 MB [64][32768][4]
  float* biasF   = (float*)(wsb + 83886080);         //  2 MB [8][64][256][4]
  fp16*  WqkvgT  = (fp16*)(wsb + 85983232);          // .5 MB [1024][256]
  fp16*  WoT     = (fp16*)(wsb + 86507520);          // .13MB [256][256]
  fp16*  gvp     = Am;                               // alias: Am dead after QKVG

  msa_wprep_k<<<2128, 256, 0, stream>>>(msa, ln_m_g, ln_m_b, Am,
                                        Wq, Wk, Wv, Wg, Wo, WqkvgT, WoT);

  mfma_gemm_k<4><<<dim3(256, 8), 256, 0, stream>>>(Am, WqkvgT, QKV16, Gfb,
                                                   nullptr, bg, 0);

  pair_bias_k<<<2048, 256, 0, stream>>>(pair, ln_p_g, ln_p_b, Wp, biasF);

  attn_k<<<dim3(128, 8), 256, 0, stream>>>(QKV16, QKV16 + NM, QKV16 + 2*NM,
                                           Gfb, biasF, gvp);

  mfma_gemm_k<2><<<dim3(256, 4), 256, 0, stream>>>(gvp, WoT, nullptr, nullptr,
                                                   out, bo, 1);
}